// Round 3
// baseline (538.739 us; speedup 1.0000x reference)
//
#include <hip/hip_runtime.h>
#include <math.h>

typedef __attribute__((ext_vector_type(8))) short short8;
typedef __attribute__((ext_vector_type(4))) float floatx4;

#define SQ 2048
#define NH 16
#define HD 128
#define NB 2
#define DM 2048
#define QKV_N 6144

__device__ __forceinline__ unsigned short f2bf(float f) {
  unsigned int x = __builtin_bit_cast(unsigned int, f);
  unsigned int r = x + 0x7fffu + ((x >> 16) & 1u);
  return (unsigned short)(r >> 16);
}
__device__ __forceinline__ float bf2f(unsigned short u) {
  unsigned int x = ((unsigned int)u) << 16;
  return __builtin_bit_cast(float, x);
}
__device__ __forceinline__ void store_c(unsigned short* p, float v) { *p = f2bf(v); }
__device__ __forceinline__ void store_c(float* p, float v) { *p = v; }

// ---------------- fp32 -> bf16 conversion (RNE), 4 elems/thread ----------------
__global__ __launch_bounds__(256) void cvt_f2b(const float* __restrict__ in,
                                               unsigned short* __restrict__ out, int n4) {
  const int i = blockIdx.x * blockDim.x + threadIdx.x;
  if (i >= n4) return;
  const float4 v = ((const float4*)in)[i];
  ushort4 o;
  o.x = f2bf(v.x); o.y = f2bf(v.y); o.z = f2bf(v.z); o.w = f2bf(v.w);
  ((ushort4*)out)[i] = o;
}

// ---------------- GEMM: C[M,N] = A[M,K] (bf16) @ W[N,K]^T (bf16) ----------------
// m97 structure: 128x128 block tile, 4 waves, 4x4 16x16x32 MFMA per wave,
// global_load_lds width=16 staging, unpadded [128][32] LDS tiles.
// OutT = unsigned short (bf16 store) or float (fp32 store).
template <typename OutT>
__global__ __launch_bounds__(256, 2) void gemm_bt(
    const unsigned short* __restrict__ A, const unsigned short* __restrict__ W,
    OutT* __restrict__ C, int M, int N, int K) {
  __shared__ __align__(16) unsigned short As[128 * 32];
  __shared__ __align__(16) unsigned short Ws[128 * 32];
  const int tid = threadIdx.x;
  const int lane = tid & 63;
  const int w = tid >> 6;
  const int wr = w >> 1, wc = w & 1;
  const int t16 = lane & 15, quad = lane >> 4;

  const long long rowA0 = (long long)blockIdx.y * 128;
  const long long colB0 = (long long)blockIdx.x * 128;
  const unsigned short* Abase = A + rowA0 * K;
  const unsigned short* Wbase = W + colB0 * K;

  const int c0 = tid, c1 = tid + 256;
  const int r0 = c0 >> 2, o0 = (c0 & 3) * 8;  // 4x 16B chunks per 32-col row
  const int r1 = c1 >> 2, o1 = (c1 & 3) * 8;

  floatx4 acc[4][4] = {};

  for (int k0 = 0; k0 < K; k0 += 32) {
    __syncthreads();
    __builtin_amdgcn_global_load_lds(
        (const __attribute__((address_space(1))) void*)(Abase + (long long)r0 * K + k0 + o0),
        (__attribute__((address_space(3))) void*)(As + c0 * 8), 16, 0, 0);
    __builtin_amdgcn_global_load_lds(
        (const __attribute__((address_space(1))) void*)(Abase + (long long)r1 * K + k0 + o1),
        (__attribute__((address_space(3))) void*)(As + c1 * 8), 16, 0, 0);
    __builtin_amdgcn_global_load_lds(
        (const __attribute__((address_space(1))) void*)(Wbase + (long long)r0 * K + k0 + o0),
        (__attribute__((address_space(3))) void*)(Ws + c0 * 8), 16, 0, 0);
    __builtin_amdgcn_global_load_lds(
        (const __attribute__((address_space(1))) void*)(Wbase + (long long)r1 * K + k0 + o1),
        (__attribute__((address_space(3))) void*)(Ws + c1 * 8), 16, 0, 0);
    __syncthreads();

    short8 a[4], b[4];
#pragma unroll
    for (int i = 0; i < 4; i++)
      a[i] = *(const short8*)(As + (wr * 64 + i * 16 + t16) * 32 + quad * 8);
#pragma unroll
    for (int j = 0; j < 4; j++)
      b[j] = *(const short8*)(Ws + (wc * 64 + j * 16 + t16) * 32 + quad * 8);
#pragma unroll
    for (int i = 0; i < 4; i++)
#pragma unroll
      for (int j = 0; j < 4; j++)
        acc[i][j] = __builtin_amdgcn_mfma_f32_16x16x32_bf16(a[i], b[j], acc[i][j], 0, 0, 0);
  }

#pragma unroll
  for (int i = 0; i < 4; i++) {
    const int rt = wr * 64 + i * 16 + quad * 4;
#pragma unroll
    for (int j = 0; j < 4; j++) {
      const long long col = colB0 + wc * 64 + j * 16 + t16;
#pragma unroll
      for (int r = 0; r < 4; r++) {
        const long long row = rowA0 + rt + r;
        store_c(&C[row * N + col], acc[i][j][r]);
      }
    }
  }
}

// ---------------- RoPE + L2 norm + scale; rearrange to (B,H,S,HD) ----------------
// one wave per (b,s,h); lane handles dims (2l, 2l+1). freqs/scale are fp32 inputs.
__global__ __launch_bounds__(256) void rope_norm(
    const unsigned short* __restrict__ qkv, const float* __restrict__ freqs,
    const float* __restrict__ scale_p,
    unsigned short* __restrict__ Qn, unsigned short* __restrict__ Kn,
    unsigned short* __restrict__ Vn) {
  const int lane = threadIdx.x & 63;
  const int g = blockIdx.x * 4 + (threadIdx.x >> 6);  // b*32768 + s*16 + h
  const int h = g & 15;
  const int s = (g >> 4) & 2047;
  const int b = g >> 15;
  const float scale = *scale_p;

  const unsigned short* qp = qkv + ((long long)(b * SQ + s)) * QKV_N + h * HD + 2 * lane;
  const unsigned int q2 = *(const unsigned int*)(qp);
  const unsigned int k2 = *(const unsigned int*)(qp + DM);
  const unsigned int v2 = *(const unsigned int*)(qp + 2 * DM);
  const float2 f2 = *(const float2*)(freqs + ((long long)s * 64 + lane) * 2);

  const float fc = f2.x, fs = f2.y;
  const float q0 = bf2f((unsigned short)(q2 & 0xffff)), q1 = bf2f((unsigned short)(q2 >> 16));
  const float k0 = bf2f((unsigned short)(k2 & 0xffff)), k1 = bf2f((unsigned short)(k2 >> 16));

  const float qr = q0 * fc - q1 * fs, qi = q0 * fs + q1 * fc;
  const float kr = k0 * fc - k1 * fs, ki = k0 * fs + k1 * fc;

  float sq = qr * qr + qi * qi;
  float sk = kr * kr + ki * ki;
#pragma unroll
  for (int m = 1; m < 64; m <<= 1) {
    sq += __shfl_xor(sq, m);
    sk += __shfl_xor(sk, m);
  }
  const float qs = scale / (sqrtf(sq) + 1e-6f);
  const float ks = 1.0f / (sqrtf(sk) + 1e-6f);

  const long long oidx = ((long long)(b * NH + h) * SQ + s) * HD + 2 * lane;
  *(unsigned int*)(Qn + oidx) = (unsigned int)f2bf(qr * qs) | ((unsigned int)f2bf(qi * qs) << 16);
  *(unsigned int*)(Kn + oidx) = (unsigned int)f2bf(kr * ks) | ((unsigned int)f2bf(ki * ks) << 16);
  *(unsigned int*)(Vn + oidx) = v2;
}

// ---------------- flash attention (causal), bf16 MFMA ----------------
// block = 4 waves, each wave one 16-row Q tile of a 64-row band; 32-key blocks.
__global__ __launch_bounds__(256, 2) void attn(
    const unsigned short* __restrict__ Qn, const unsigned short* __restrict__ Kn,
    const unsigned short* __restrict__ Vn, unsigned short* __restrict__ Oout) {
  __shared__ __align__(16) unsigned short Ks[32 * 136];   // K rows, padded stride 136
  __shared__ __align__(16) unsigned short Vt[128 * 40];   // V transposed [d][key], stride 40
  __shared__ __align__(16) unsigned short Pw[4][16 * 40]; // per-wave P, stride 40

  const int tid = threadIdx.x;
  const int lane = tid & 63;
  const int w = tid >> 6;
  const int t16 = lane & 15, quad = lane >> 4;
  const int bh = blockIdx.y;            // b*NH + h
  const int qb = blockIdx.x * 64;
  const long long base = (long long)bh * SQ * HD;

  // Q fragments (A layout: m=t16, k=quad*8+j), kept in registers all kernel
  short8 qf[4];
  const int qrow = qb + w * 16 + t16;
#pragma unroll
  for (int c = 0; c < 4; c++)
    qf[c] = *(const short8*)(Qn + base + (long long)qrow * HD + c * 32 + quad * 8);

  floatx4 o[8] = {};
  float m_r[4] = {-1e30f, -1e30f, -1e30f, -1e30f};
  float l_r[4] = {0.f, 0.f, 0.f, 0.f};
  const int qr0 = qb + w * 16 + quad * 4;  // C-layout row base
  const int kend = qb + 64;

  for (int kb = 0; kb < kend; kb += 32) {
    __syncthreads();
    // stage K tile rows [kb, kb+32), padded stride 136
#pragma unroll
    for (int cc = 0; cc < 2; cc++) {
      const int c = tid + cc * 256;
      const int row = c >> 4, off = (c & 15) * 8;
      const uint4 d = *(const uint4*)(Kn + base + (long long)(kb + row) * HD + off);
      *(uint4*)(Ks + row * 136 + off) = d;
    }
    // stage V transposed: thread packs key pair (kk0,kk0+1) for 8 dims
    {
      const int kk0 = (tid & 15) * 2;
      const int d0 = (tid >> 4) * 8;
      const unsigned short* vp = Vn + base + (long long)(kb + kk0) * HD + d0;
      const short8 v0 = *(const short8*)(vp);
      const short8 v1 = *(const short8*)(vp + HD);
#pragma unroll
      for (int jj = 0; jj < 8; jj++) {
        const unsigned int pk = (unsigned int)(unsigned short)v0[jj] |
                                ((unsigned int)(unsigned short)v1[jj] << 16);
        *(unsigned int*)(Vt + (d0 + jj) * 40 + kk0) = pk;
      }
    }
    __syncthreads();

    // scores: 16 q x 32 keys, fp32 accum
    floatx4 sc0 = {}, sc1 = {};
#pragma unroll
    for (int c = 0; c < 4; c++) {
      const short8 kf0 = *(const short8*)(Ks + t16 * 136 + c * 32 + quad * 8);
      const short8 kf1 = *(const short8*)(Ks + (16 + t16) * 136 + c * 32 + quad * 8);
      sc0 = __builtin_amdgcn_mfma_f32_16x16x32_bf16(qf[c], kf0, sc0, 0, 0, 0);
      sc1 = __builtin_amdgcn_mfma_f32_16x16x32_bf16(qf[c], kf1, sc1, 0, 0, 0);
    }
    // causal mask (C layout: row=qr0+r, col=kb+{0,16}+t16)
#pragma unroll
    for (int r = 0; r < 4; r++) {
      if (kb + t16 > qr0 + r) sc0[r] = -1e30f;
      if (kb + 16 + t16 > qr0 + r) sc1[r] = -1e30f;
    }
    // online softmax per row (reduce across 16 lanes of same quad)
    float p0[4], p1[4];
    floatx4 av;
#pragma unroll
    for (int r = 0; r < 4; r++) {
      float v = fmaxf(sc0[r], sc1[r]);
      v = fmaxf(v, __shfl_xor(v, 1));
      v = fmaxf(v, __shfl_xor(v, 2));
      v = fmaxf(v, __shfl_xor(v, 4));
      v = fmaxf(v, __shfl_xor(v, 8));
      const float mn = fmaxf(m_r[r], v);
      const float al = __expf(m_r[r] - mn);
      m_r[r] = mn;
      p0[r] = __expf(sc0[r] - mn);
      p1[r] = __expf(sc1[r] - mn);
      float rs = p0[r] + p1[r];
      rs += __shfl_xor(rs, 1);
      rs += __shfl_xor(rs, 2);
      rs += __shfl_xor(rs, 4);
      rs += __shfl_xor(rs, 8);
      l_r[r] = l_r[r] * al + rs;
      av[r] = al;
    }
#pragma unroll
    for (int dc = 0; dc < 8; dc++) o[dc] *= av;

    // P: C layout -> LDS -> A layout (m120-verified transform), bf16
    unsigned short* pw = &Pw[w][0];
#pragma unroll
    for (int r = 0; r < 4; r++) {
      pw[(quad * 4 + r) * 40 + t16] = f2bf(p0[r]);
      pw[(quad * 4 + r) * 40 + 16 + t16] = f2bf(p1[r]);
    }
    asm volatile("s_waitcnt lgkmcnt(0)" ::: "memory");  // same-wave LDS WAR/RAW fence
    const short8 pf = *(const short8*)(pw + t16 * 40 + quad * 8);
    // PV: B frag from Vt is contiguous 16B per lane
#pragma unroll
    for (int dc = 0; dc < 8; dc++) {
      const short8 vf = *(const short8*)(Vt + (dc * 16 + t16) * 40 + quad * 8);
      o[dc] = __builtin_amdgcn_mfma_f32_16x16x32_bf16(pf, vf, o[dc], 0, 0, 0);
    }
  }

  // epilogue: O/l, write to (B,S,D) bf16 for out-proj GEMM
  const int b = bh >> 4, h = bh & 15;
#pragma unroll
  for (int dc = 0; dc < 8; dc++) {
#pragma unroll
    for (int r = 0; r < 4; r++) {
      const int q = qb + w * 16 + quad * 4 + r;
      Oout[(long long)(b * SQ + q) * DM + h * HD + dc * 16 + t16] = f2bf(o[dc][r] / l_r[r]);
    }
  }
}

extern "C" void kernel_launch(void* const* d_in, const int* in_sizes, int n_in,
                              void* d_out, int out_size, void* d_ws, size_t ws_size,
                              hipStream_t stream) {
  const float* x = (const float*)d_in[0];          // fp32 (B,S,D)
  const float* freqs = (const float*)d_in[1];      // fp32 (S,HD/2,2)
  const float* w_qkv = (const float*)d_in[2];      // fp32 (3D,D)
  const float* w_out = (const float*)d_in[3];      // fp32 (D,D)
  const float* attn_scale = (const float*)d_in[4]; // fp32 scalar
  float* out = (float*)d_out;                      // fp32 (B,S,D)

  char* ws = (char*)d_ws;
  // layout (bytes):
  //   [0, 50331648)              qkv bf16 4096x6144  (aliased by attn_o after rope_norm)
  //   [50331648, 100663296)      Qn/Kn/Vn bf16 (B,H,S,HD) x3
  //   [100663296, 117440512)     x_b bf16 4096x2048
  //   [117440512, 142606336)     w_qkv_b bf16 6144x2048
  //   [142606336, 150994944)     w_out_b bf16 2048x2048       total 144 MB
  unsigned short* qkv = (unsigned short*)ws;
  unsigned short* attn_o = (unsigned short*)ws;  // alias: qkv dead after rope_norm
  unsigned short* Qn = (unsigned short*)(ws + 50331648);
  unsigned short* Kn = Qn + (size_t)NB * NH * SQ * HD;
  unsigned short* Vn = Kn + (size_t)NB * NH * SQ * HD;
  unsigned short* x_b = (unsigned short*)(ws + 100663296);
  unsigned short* w_qkv_b = (unsigned short*)(ws + 117440512);
  unsigned short* w_out_b = (unsigned short*)(ws + 142606336);

  // fp32 -> bf16 conversions
  cvt_f2b<<<dim3((NB * SQ * DM / 4 + 255) / 256), 256, 0, stream>>>(x, x_b, NB * SQ * DM / 4);
  cvt_f2b<<<dim3((3 * DM * DM / 4 + 255) / 256), 256, 0, stream>>>(w_qkv, w_qkv_b, 3 * DM * DM / 4);
  cvt_f2b<<<dim3((DM * DM / 4 + 255) / 256), 256, 0, stream>>>(w_out, w_out_b, DM * DM / 4);

  // qkv = x @ w_qkv^T   (M=4096, N=6144, K=2048), bf16 out
  gemm_bt<unsigned short><<<dim3(QKV_N / 128, (NB * SQ) / 128), 256, 0, stream>>>(
      x_b, w_qkv_b, qkv, NB * SQ, QKV_N, DM);
  // rope + norm + scale + rearrange
  rope_norm<<<dim3((NB * SQ * NH) / 4), 256, 0, stream>>>(qkv, freqs, attn_scale, Qn, Kn, Vn);
  // causal flash attention
  attn<<<dim3(SQ / 64, NB * NH), 256, 0, stream>>>(Qn, Kn, Vn, attn_o);
  // out = attn_o @ w_out^T  (M=4096, N=2048, K=2048), fp32 out
  gemm_bt<float><<<dim3(DM / 128, (NB * SQ) / 128), 256, 0, stream>>>(
      attn_o, w_out_b, out, NB * SQ, DM, DM);
}

// Round 5
// 420.578 us; speedup vs baseline: 1.2809x; 1.2809x over previous
//
#include <hip/hip_runtime.h>
#include <math.h>

typedef __attribute__((ext_vector_type(8))) short short8;
typedef __attribute__((ext_vector_type(4))) float floatx4;

#define SQ 2048
#define NH 16
#define HD 128
#define NB 2
#define DM 2048
#define QKV_N 6144

__device__ __forceinline__ unsigned short f2bf(float f) {
  unsigned int x = __builtin_bit_cast(unsigned int, f);
  unsigned int r = x + 0x7fffu + ((x >> 16) & 1u);
  return (unsigned short)(r >> 16);
}
__device__ __forceinline__ float bf2f(unsigned short u) {
  unsigned int x = ((unsigned int)u) << 16;
  return __builtin_bit_cast(float, x);
}
__device__ __forceinline__ void store_c(unsigned short* p, float v) { *p = f2bf(v); }
__device__ __forceinline__ void store_c(float* p, float v) { *p = v; }

// ---------------- fp32 -> bf16 conversion (RNE), 4 elems/thread ----------------
__global__ __launch_bounds__(256) void cvt_f2b(const float* __restrict__ in,
                                               unsigned short* __restrict__ out, int n4) {
  const int i = blockIdx.x * blockDim.x + threadIdx.x;
  if (i >= n4) return;
  const float4 v = ((const float4*)in)[i];
  ushort4 o;
  o.x = f2bf(v.x); o.y = f2bf(v.y); o.z = f2bf(v.z); o.w = f2bf(v.w);
  ((ushort4*)out)[i] = o;
}

// ---------------- GEMM: C[M,N] = A[M,K] (bf16) @ W[N,K]^T (bf16) ----------------
// m97 structure: 128x128 tile, 4 waves, 4x4 16x16x32 MFMA, global_load_lds width=16.
template <typename OutT>
__global__ __launch_bounds__(256, 2) void gemm_bt(
    const unsigned short* __restrict__ A, const unsigned short* __restrict__ W,
    OutT* __restrict__ C, int M, int N, int K) {
  __shared__ __align__(16) unsigned short As[128 * 32];
  __shared__ __align__(16) unsigned short Ws[128 * 32];
  const int tid = threadIdx.x;
  const int lane = tid & 63;
  const int w = tid >> 6;
  const int wr = w >> 1, wc = w & 1;
  const int t16 = lane & 15, quad = lane >> 4;

  const long long rowA0 = (long long)blockIdx.y * 128;
  const long long colB0 = (long long)blockIdx.x * 128;
  const unsigned short* Abase = A + rowA0 * K;
  const unsigned short* Wbase = W + colB0 * K;

  const int c0 = tid, c1 = tid + 256;
  const int r0 = c0 >> 2, o0 = (c0 & 3) * 8;
  const int r1 = c1 >> 2, o1 = (c1 & 3) * 8;

  floatx4 acc[4][4] = {};

  for (int k0 = 0; k0 < K; k0 += 32) {
    __syncthreads();
    __builtin_amdgcn_global_load_lds(
        (const __attribute__((address_space(1))) void*)(Abase + (long long)r0 * K + k0 + o0),
        (__attribute__((address_space(3))) void*)(As + c0 * 8), 16, 0, 0);
    __builtin_amdgcn_global_load_lds(
        (const __attribute__((address_space(1))) void*)(Abase + (long long)r1 * K + k0 + o1),
        (__attribute__((address_space(3))) void*)(As + c1 * 8), 16, 0, 0);
    __builtin_amdgcn_global_load_lds(
        (const __attribute__((address_space(1))) void*)(Wbase + (long long)r0 * K + k0 + o0),
        (__attribute__((address_space(3))) void*)(Ws + c0 * 8), 16, 0, 0);
    __builtin_amdgcn_global_load_lds(
        (const __attribute__((address_space(1))) void*)(Wbase + (long long)r1 * K + k0 + o1),
        (__attribute__((address_space(3))) void*)(Ws + c1 * 8), 16, 0, 0);
    __syncthreads();

    short8 a[4], b[4];
#pragma unroll
    for (int i = 0; i < 4; i++)
      a[i] = *(const short8*)(As + (wr * 64 + i * 16 + t16) * 32 + quad * 8);
#pragma unroll
    for (int j = 0; j < 4; j++)
      b[j] = *(const short8*)(Ws + (wc * 64 + j * 16 + t16) * 32 + quad * 8);
#pragma unroll
    for (int i = 0; i < 4; i++)
#pragma unroll
      for (int j = 0; j < 4; j++)
        acc[i][j] = __builtin_amdgcn_mfma_f32_16x16x32_bf16(a[i], b[j], acc[i][j], 0, 0, 0);
  }

#pragma unroll
  for (int i = 0; i < 4; i++) {
    const int rt = wr * 64 + i * 16 + quad * 4;
#pragma unroll
    for (int j = 0; j < 4; j++) {
      const long long col = colB0 + wc * 64 + j * 16 + t16;
#pragma unroll
      for (int r = 0; r < 4; r++) {
        const long long row = rowA0 + rt + r;
        store_c(&C[row * N + col], acc[i][j][r]);
      }
    }
  }
}

// ---------------- RoPE + L2 norm + scale; rearrange to (B,H,S,HD) ----------------
__global__ __launch_bounds__(256) void rope_norm(
    const unsigned short* __restrict__ qkv, const float* __restrict__ freqs,
    const float* __restrict__ scale_p,
    unsigned short* __restrict__ Qn, unsigned short* __restrict__ Kn,
    unsigned short* __restrict__ Vn) {
  const int lane = threadIdx.x & 63;
  const int g = blockIdx.x * 4 + (threadIdx.x >> 6);  // b*32768 + s*16 + h
  const int h = g & 15;
  const int s = (g >> 4) & 2047;
  const int b = g >> 15;
  const float scale = *scale_p;

  const unsigned short* qp = qkv + ((long long)(b * SQ + s)) * QKV_N + h * HD + 2 * lane;
  const unsigned int q2 = *(const unsigned int*)(qp);
  const unsigned int k2 = *(const unsigned int*)(qp + DM);
  const unsigned int v2 = *(const unsigned int*)(qp + 2 * DM);
  const float2 f2 = *(const float2*)(freqs + ((long long)s * 64 + lane) * 2);

  const float fc = f2.x, fs = f2.y;
  const float q0 = bf2f((unsigned short)(q2 & 0xffff)), q1 = bf2f((unsigned short)(q2 >> 16));
  const float k0 = bf2f((unsigned short)(k2 & 0xffff)), k1 = bf2f((unsigned short)(k2 >> 16));

  const float qr = q0 * fc - q1 * fs, qi = q0 * fs + q1 * fc;
  const float kr = k0 * fc - k1 * fs, ki = k0 * fs + k1 * fc;

  float sq = qr * qr + qi * qi;
  float sk = kr * kr + ki * ki;
#pragma unroll
  for (int m = 1; m < 64; m <<= 1) {
    sq += __shfl_xor(sq, m);
    sk += __shfl_xor(sk, m);
  }
  const float qs = scale / (sqrtf(sq) + 1e-6f);
  const float ks = 1.0f / (sqrtf(sk) + 1e-6f);

  const long long oidx = ((long long)(b * NH + h) * SQ + s) * HD + 2 * lane;
  *(unsigned int*)(Qn + oidx) = (unsigned int)f2bf(qr * qs) | ((unsigned int)f2bf(qi * qs) << 16);
  *(unsigned int*)(Kn + oidx) = (unsigned int)f2bf(kr * ks) | ((unsigned int)f2bf(ki * ks) << 16);
  *(unsigned int*)(Vn + oidx) = v2;
}

// ---------------- flash attention (causal), round-3 body + pairing + fixed-max ----------------
// block = 4 waves; processes band pair (pb, 31-pb) of 64 q-rows each -> uniform 66 iters.
__global__ __launch_bounds__(256, 2) void attn(
    const unsigned short* __restrict__ Qn, const unsigned short* __restrict__ Kn,
    const unsigned short* __restrict__ Vn, const float* __restrict__ scale_p,
    unsigned short* __restrict__ Oout) {
  __shared__ __align__(16) unsigned short Ks[32 * 136];   // K rows, padded stride 136
  __shared__ __align__(16) unsigned short Vt[128 * 40];   // V transposed [d][key], stride 40
  __shared__ __align__(16) unsigned short Pw[4][16 * 40]; // per-wave P, stride 40

  const int tid = threadIdx.x;
  const int lane = tid & 63;
  const int w = tid >> 6;
  const int t16 = lane & 15, quad = lane >> 4;
  // XCD swizzle: k%8 = xcd; each xcd gets 4 consecutive heads (L2 locality)
  const int k = blockIdx.x + 16 * blockIdx.y;  // 0..511
  const int xcd = k & 7, i = k >> 3;
  const int bh = (xcd << 2) | (i & 3);  // 0..31
  const int pb = i >> 2;                // 0..15: band pair (pb, 31-pb)
  const float M = *scale_p;
  const long long base = (long long)bh * SQ * HD;
  const int b = bh >> 4, h = bh & 15;
  unsigned short* pw = &Pw[w][0];

#pragma unroll
  for (int t = 0; t < 2; t++) {
    const int qb = (t == 0) ? 64 * pb : 64 * (31 - pb);

    // Q fragments (A layout: m=t16, k=quad*8+j)
    short8 qf[4];
    const int qrow = qb + w * 16 + t16;
#pragma unroll
    for (int c = 0; c < 4; c++)
      qf[c] = *(const short8*)(Qn + base + (long long)qrow * HD + c * 32 + quad * 8);

    floatx4 o[8] = {};
    float l[4] = {0.f, 0.f, 0.f, 0.f};
    const int qr0 = qb + w * 16 + quad * 4;  // C-layout row base
    const int kend = qb + 64;

    for (int kb = 0; kb < kend; kb += 32) {
      __syncthreads();
      // stage K tile rows [kb, kb+32), padded stride 136
#pragma unroll
      for (int cc = 0; cc < 2; cc++) {
        const int c = tid + cc * 256;
        const int row = c >> 4, off = (c & 15) * 8;
        const uint4 d = *(const uint4*)(Kn + base + (long long)(kb + row) * HD + off);
        *(uint4*)(Ks + row * 136 + off) = d;
      }
      // stage V transposed: thread packs key pair (kk0,kk0+1) for 8 dims
      {
        const int kk0 = (tid & 15) * 2;
        const int d0 = (tid >> 4) * 8;
        const unsigned short* vp = Vn + base + (long long)(kb + kk0) * HD + d0;
        const short8 v0 = *(const short8*)(vp);
        const short8 v1 = *(const short8*)(vp + HD);
#pragma unroll
        for (int jj = 0; jj < 8; jj++) {
          const unsigned int pk = (unsigned int)(unsigned short)v0[jj] |
                                  ((unsigned int)(unsigned short)v1[jj] << 16);
          *(unsigned int*)(Vt + (d0 + jj) * 40 + kk0) = pk;
        }
      }
      __syncthreads();

      // scores: 16 q x 32 keys, fp32 accum
      floatx4 sc0 = {}, sc1 = {};
#pragma unroll
      for (int c = 0; c < 4; c++) {
        const short8 kf0 = *(const short8*)(Ks + t16 * 136 + c * 32 + quad * 8);
        const short8 kf1 = *(const short8*)(Ks + (16 + t16) * 136 + c * 32 + quad * 8);
        sc0 = __builtin_amdgcn_mfma_f32_16x16x32_bf16(qf[c], kf0, sc0, 0, 0, 0);
        sc1 = __builtin_amdgcn_mfma_f32_16x16x32_bf16(qf[c], kf1, sc1, 0, 0, 0);
      }
      // fixed-max softmax (scores <= M by construction) + causal mask -> p, l
#pragma unroll
      for (int r = 0; r < 4; r++) {
        float e0 = __expf(sc0[r] - M);
        float e1 = __expf(sc1[r] - M);
        e0 = (kb + t16 <= qr0 + r) ? e0 : 0.f;
        e1 = (kb + 16 + t16 <= qr0 + r) ? e1 : 0.f;
        l[r] += e0 + e1;
        pw[(quad * 4 + r) * 40 + t16] = f2bf(e0);
        pw[(quad * 4 + r) * 40 + 16 + t16] = f2bf(e1);
      }
      asm volatile("s_waitcnt lgkmcnt(0)" ::: "memory");  // same-wave LDS WAR/RAW fence
      const short8 pf = *(const short8*)(pw + t16 * 40 + quad * 8);
      // PV: B frag from Vt is contiguous 16B per lane
#pragma unroll
      for (int dc = 0; dc < 8; dc++) {
        const short8 vf = *(const short8*)(Vt + (dc * 16 + t16) * 40 + quad * 8);
        o[dc] = __builtin_amdgcn_mfma_f32_16x16x32_bf16(pf, vf, o[dc], 0, 0, 0);
      }
    }

    // l: reduce across the 16 lanes of the quad-row group, then epilogue
    float linv[4];
#pragma unroll
    for (int r = 0; r < 4; r++) {
      float s = l[r];
      s += __shfl_xor(s, 1);
      s += __shfl_xor(s, 2);
      s += __shfl_xor(s, 4);
      s += __shfl_xor(s, 8);
      linv[r] = 1.0f / s;
    }
#pragma unroll
    for (int dc = 0; dc < 8; dc++)
#pragma unroll
      for (int r = 0; r < 4; r++) {
        const int q = qb + w * 16 + quad * 4 + r;
        Oout[(long long)(b * SQ + q) * DM + h * HD + dc * 16 + t16] =
            f2bf(o[dc][r] * linv[r]);
      }
  }
}

extern "C" void kernel_launch(void* const* d_in, const int* in_sizes, int n_in,
                              void* d_out, int out_size, void* d_ws, size_t ws_size,
                              hipStream_t stream) {
  const float* x = (const float*)d_in[0];
  const float* freqs = (const float*)d_in[1];
  const float* w_qkv = (const float*)d_in[2];
  const float* w_out = (const float*)d_in[3];
  const float* attn_scale = (const float*)d_in[4];
  float* out = (float*)d_out;

  char* ws = (char*)d_ws;
  // [0, 50331648)         qkv bf16 4096x6144 (aliased by attn_o after rope_norm)
  // [50331648, +16M each) Qn / Kn / Vn bf16 (B,H,S,HD)
  // [100663296, ...)      x_b / w_qkv_b / w_out_b
  unsigned short* qkv = (unsigned short*)ws;
  unsigned short* attn_o = (unsigned short*)ws;
  unsigned short* Qn = (unsigned short*)(ws + 50331648);
  unsigned short* Kn = Qn + (size_t)NB * NH * SQ * HD;
  unsigned short* Vn = Kn + (size_t)NB * NH * SQ * HD;
  unsigned short* x_b = (unsigned short*)(ws + 100663296);
  unsigned short* w_qkv_b = (unsigned short*)(ws + 117440512);
  unsigned short* w_out_b = (unsigned short*)(ws + 142606336);

  cvt_f2b<<<dim3((NB * SQ * DM / 4 + 255) / 256), 256, 0, stream>>>(x, x_b, NB * SQ * DM / 4);
  cvt_f2b<<<dim3((3 * DM * DM / 4 + 255) / 256), 256, 0, stream>>>(w_qkv, w_qkv_b, 3 * DM * DM / 4);
  cvt_f2b<<<dim3((DM * DM / 4 + 255) / 256), 256, 0, stream>>>(w_out, w_out_b, DM * DM / 4);

  gemm_bt<unsigned short><<<dim3(QKV_N / 128, (NB * SQ) / 128), 256, 0, stream>>>(
      x_b, w_qkv_b, qkv, NB * SQ, QKV_N, DM);
  rope_norm<<<dim3((NB * SQ * NH) / 4), 256, 0, stream>>>(qkv, freqs, attn_scale, Qn, Kn, Vn);
  attn<<<dim3(16, 32), 256, 0, stream>>>(Qn, Kn, Vn, attn_scale, attn_o);
  gemm_bt<float><<<dim3(DM / 128, (NB * SQ) / 128), 256, 0, stream>>>(
      attn_o, w_out_b, out, NB * SQ, DM, DM);
}